// Round 7
// baseline (382.233 us; speedup 1.0000x reference)
//
#include <hip/hip_runtime.h>

#define N_EVENTS 16384
#define DIM 128
#define NK 9
#define NSEQ 2048
#define TT 147456
#define CHUNK 64
#define NCHUNK_MAX (TT/CHUNK + NK)   // 2313
#define NHBLK 576                    // TT / 256 exactly

typedef __attribute__((ext_vector_type(8))) short bf16x8;
typedef __attribute__((ext_vector_type(4))) float f32x4;
typedef __attribute__((ext_vector_type(4))) int i32x4;

// ---- workspace layout (bytes) ----
#define OFF_EV     0UL                                     // events bf16: 16384*128*2
#define OFF_WC     (OFF_EV   + (size_t)N_EVENTS*DIM*2)     // [w_ih|w_hh] bf16: 512*256*2
#define OFF_SCAT   (OFF_WC   + (size_t)512*256*2)          // scatter_w bf16
#define OFF_GATH   (OFF_SCAT + (size_t)NK*DIM*DIM*2)       // gather_w bf16
#define OFF_XS     (OFF_GATH + (size_t)NK*DIM*DIM*2)       // xs bf16: T*128*2
#define OFF_HS     (OFF_XS   + (size_t)TT*DIM*2)           // h bf16: T*128*2
#define OFF_KLIST  (OFF_HS   + (size_t)TT*DIM*2)           // k-sorted token ids
#define OFF_ACC    (OFF_KLIST+ (size_t)TT*4)               // accum f32: 16384*128*4
#define OFF_SEQOFF (OFF_ACC  + (size_t)N_EVENTS*DIM*4)
#define OFF_GROUP  (OFF_SEQOFF + (size_t)NSEQ*4)
#define OFF_MISC   (OFF_GROUP  + (size_t)NSEQ*4)
#define OFF_BH     (OFF_MISC   + 256UL)                    // blockhist: 576*9 ints
// misc ints: [0..8]=kcount  [32..40]=koff  [48..57]=choff

__device__ __forceinline__ short f2b(float f) {
    union { float f; unsigned u; } v; v.f = f;
    unsigned r = (v.u + 0x7FFFu + ((v.u >> 16) & 1u)) >> 16;
    return (short)r;
}

// convert + zero fused: grid covers exactly N_EVENTS*DIM = 2.1M threads
__global__ void convert_kernel(const float* __restrict__ ev, const float* __restrict__ wih,
                               const float* __restrict__ whh, const float* __restrict__ sw,
                               const float* __restrict__ gw,
                               short* __restrict__ evb, short* __restrict__ wcb,
                               short* __restrict__ swb, short* __restrict__ gwb,
                               float* __restrict__ acc) {
    int idx = blockIdx.x * blockDim.x + threadIdx.x;
    if (idx < N_EVENTS * DIM) { evb[idx] = f2b(ev[idx]); acc[idx] = 0.f; }
    if (idx < 512 * DIM) {
        int j = idx >> 7, d = idx & 127;
        wcb[j * 256 + d]       = f2b(wih[idx]);
        wcb[j * 256 + 128 + d] = f2b(whh[idx]);
    }
    if (idx < NK * DIM * DIM) { swb[idx] = f2b(sw[idx]); gwb[idx] = f2b(gw[idx]); }
}

// per-block 9-bin histogram (LDS atomics only — zero global atomics)
__global__ void hist_kernel(const int* __restrict__ pos, int* __restrict__ blockhist) {
    __shared__ int h[NK];
    int tid = threadIdx.x;
    if (tid < NK) h[tid] = 0;
    __syncthreads();
    atomicAdd(&h[pos[blockIdx.x * 256 + tid]], 1);
    __syncthreads();
    if (tid < NK) blockhist[blockIdx.x * NK + tid] = h[tid];
}

// single-block scan: per-block exclusive offsets per bin + global bin/chunk offsets
__global__ void scan_kernel(int* __restrict__ blockhist, int* __restrict__ misc) {
    __shared__ int h[NHBLK * NK];
    int tid = threadIdx.x;
    for (int i = tid; i < NHBLK * NK; i += 256) h[i] = blockhist[i];
    __syncthreads();
    if (tid < NK) {
        int run = 0;
        for (int b = 0; b < NHBLK; b++) {
            int v = h[b * NK + tid];
            h[b * NK + tid] = run;
            run += v;
        }
        misc[tid] = run;                 // total count per k
    }
    __syncthreads();
    if (tid == 0) {
        int ko = 0, co = 0;
        for (int k = 0; k < NK; k++) {
            int c = misc[k];
            misc[32 + k] = ko;
            misc[48 + k] = co;
            ko += c;
            co += (c + CHUNK - 1) / CHUNK;
        }
        misc[48 + NK] = co;
    }
    __syncthreads();
    for (int i = tid; i < NHBLK * NK; i += 256) blockhist[i] = h[i];
}

__global__ void setup_kernel(const int* __restrict__ lengths,
                             int* __restrict__ seq_off, int* __restrict__ grouped) {
    __shared__ int lens[NSEQ];
    __shared__ int tsum[256], tlong[256];
    int tid = threadIdx.x;
    for (int i = tid; i < NSEQ; i += 256) lens[i] = lengths[i];
    __syncthreads();
    int base = tid * 8;
    int ls[8]; int s = 0, lc = 0;
    #pragma unroll
    for (int i = 0; i < 8; i++) { ls[i] = lens[base + i]; s += ls[i]; lc += (ls[i] > 64) ? 1 : 0; }
    tsum[tid] = s; tlong[tid] = lc;
    __syncthreads();
    for (int d = 1; d < 256; d <<= 1) {
        int a = (tid >= d) ? tsum[tid - d] : 0;
        int b = (tid >= d) ? tlong[tid - d] : 0;
        __syncthreads();
        tsum[tid] += a; tlong[tid] += b;
        __syncthreads();
    }
    int nlong_total = tlong[255];
    int excl = tsum[tid] - s;
    int excl_long = tlong[tid] - lc;
    int run = 0, runl = 0;
    #pragma unroll
    for (int i = 0; i < 8; i++) {
        int sid = base + i;
        seq_off[sid] = excl + run;
        int longs_before = excl_long + runl;
        if (ls[i] > 64) { grouped[longs_before] = sid; runl++; }
        else            { grouped[nlong_total + (sid - longs_before)] = sid; }
        run += ls[i];
    }
}

// scatter token ids to their bin positions (LDS atomics for intra-block rank)
__global__ void fill2_kernel(const int* __restrict__ pos, const int* __restrict__ blockhist,
                             const int* __restrict__ misc, int* __restrict__ klist) {
    __shared__ int off[NK];
    int tid = threadIdx.x;
    if (tid < NK) off[tid] = misc[32 + tid] + blockhist[blockIdx.x * NK + tid];
    __syncthreads();
    int t = blockIdx.x * 256 + tid;
    int p = atomicAdd(&off[pos[t]], 1);
    klist[p] = t;
}

// mode 0: rows = events[orig[tok]], write bf16 rows to xs_out[tok]
// mode 1: rows = hstore[tok],       atomicAdd f32 C into acc[orig[tok]]
__global__ void bucket_gemm(const short* __restrict__ src, const short* __restrict__ wall,
                            const int* __restrict__ klist, const int* __restrict__ misc,
                            const int* __restrict__ orig, short* __restrict__ xs_out,
                            float* __restrict__ acc, int mode) {
    const int* chunkoff = misc + 48;
    int b = blockIdx.x;
    if (b >= chunkoff[NK]) return;
    int k = 0;
    while (k < NK - 1 && chunkoff[k + 1] <= b) k++;
    int lc = b - chunkoff[k];
    int cnt = misc[k];
    int base = misc[32 + k] + lc * CHUNK;
    int nv = min(CHUNK, cnt - lc * CHUNK);

    __shared__ int tok[CHUNK], dst[CHUNK];
    __shared__ short A[CHUNK * 136];
    int tid = threadIdx.x;
    if (tid < CHUNK) {
        int tv = klist[base + ((tid < nv) ? tid : 0)];
        tok[tid] = tv;
        dst[tid] = orig[tv];
    }
    __syncthreads();
    {
        int row = tid >> 2, part = tid & 3;
        int ridx = (mode == 0) ? dst[row] : tok[row];
        const i32x4* s4 = (const i32x4*)(src + (size_t)ridx * DIM + part * 32);
        i32x4* d4 = (i32x4*)(A + row * 136 + part * 32);
        d4[0] = s4[0]; d4[1] = s4[1]; d4[2] = s4[2]; d4[3] = s4[3];
    }
    __syncthreads();
    int wave = tid >> 6, lane = tid & 63, l15 = lane & 15, q = lane >> 4;
    const short* wk = wall + (size_t)k * DIM * DIM;
    bf16x8 Bf[2][4];
    #pragma unroll
    for (int nt = 0; nt < 2; nt++) {
        int h = wave * 32 + nt * 16 + l15;
        #pragma unroll
        for (int kt = 0; kt < 4; kt++)
            Bf[nt][kt] = *(const bf16x8*)(wk + h * DIM + kt * 32 + q * 8);
    }
    f32x4 C[4][2];
    #pragma unroll
    for (int mt = 0; mt < 4; mt++)
        #pragma unroll
        for (int nt = 0; nt < 2; nt++) C[mt][nt] = (f32x4){0.f, 0.f, 0.f, 0.f};
    #pragma unroll
    for (int mt = 0; mt < 4; mt++) {
        bf16x8 Afr[4];
        const short* ar = A + (mt * 16 + l15) * 136 + q * 8;
        Afr[0] = *(const bf16x8*)(ar);
        Afr[1] = *(const bf16x8*)(ar + 32);
        Afr[2] = *(const bf16x8*)(ar + 64);
        Afr[3] = *(const bf16x8*)(ar + 96);
        #pragma unroll
        for (int nt = 0; nt < 2; nt++)
            #pragma unroll
            for (int kt = 0; kt < 4; kt++)
                C[mt][nt] = __builtin_amdgcn_mfma_f32_16x16x32_bf16(Afr[kt], Bf[nt][kt], C[mt][nt], 0, 0, 0);
    }
    if (mode == 0) {
        __syncthreads();
        #pragma unroll
        for (int mt = 0; mt < 4; mt++)
            #pragma unroll
            for (int nt = 0; nt < 2; nt++)
                #pragma unroll
                for (int r = 0; r < 4; r++) {
                    int row = mt * 16 + q * 4 + r;
                    int col = wave * 32 + nt * 16 + l15;
                    A[row * 136 + col] = f2b(C[mt][nt][r]);
                }
        __syncthreads();
        int row = tid >> 2, part = tid & 3;
        if (row < nv) {
            const i32x4* s4 = (const i32x4*)(A + row * 136 + part * 32);
            i32x4* d4 = (i32x4*)(xs_out + (size_t)tok[row] * DIM + part * 32);
            d4[0] = s4[0]; d4[1] = s4[1]; d4[2] = s4[2]; d4[3] = s4[3];
        }
    } else {
        #pragma unroll
        for (int mt = 0; mt < 4; mt++)
            #pragma unroll
            for (int nt = 0; nt < 2; nt++)
                #pragma unroll
                for (int r = 0; r < 4; r++) {
                    int row = mt * 16 + q * 4 + r;
                    if (row < nv) {
                        int col = wave * 32 + nt * 16 + l15;
                        atomicAdd(acc + (size_t)dst[row] * DIM + col, C[mt][nt][r]);
                    }
                }
    }
}

#define MF(a, b, c) __builtin_amdgcn_mfma_f32_16x16x32_bf16(a, b, c, 0, 0, 0)

// One LSTM step, compile-time slot J (0..7). hchunk ring: gates write h to slot J,
// MFMA reads h from slot (J+7)&7. Gate exchange through padded LDS gbuf.
#define LSTM_STEP(J) { \
    const int i_ = ib8 + (J); \
    const short* hp_ = hb + (((J) + 7) & 7) * 1088 + l15 * 136 + ql * 8; \
    bf16x8 Hf0 = *(const bf16x8*)(hp_); \
    bf16x8 Hf1 = *(const bf16x8*)(hp_ + 32); \
    bf16x8 Hf2 = *(const bf16x8*)(hp_ + 64); \
    bf16x8 Hf3 = *(const bf16x8*)(hp_ + 96); \
    f32x4 C0 = {0.f,0.f,0.f,0.f}, C1 = {0.f,0.f,0.f,0.f}; \
    C0 = MF(Pf[0], Bx[0][0], C0);  C1 = MF(Pf[0], Bx[1][0], C1); \
    C0 = MF(Pf[1], Bx[0][1], C0);  C1 = MF(Pf[1], Bx[1][1], C1); \
    C0 = MF(Pf[2], Bx[0][2], C0);  C1 = MF(Pf[2], Bx[1][2], C1); \
    C0 = MF(Pf[3], Bx[0][3], C0);  C1 = MF(Pf[3], Bx[1][3], C1); \
    C0 = MF(Hf0, Bh[0][0], C0);    C1 = MF(Hf0, Bh[1][0], C1); \
    C0 = MF(Hf1, Bh[0][1], C0);    C1 = MF(Hf1, Bh[1][1], C1); \
    C0 = MF(Hf2, Bh[0][2], C0);    C1 = MF(Hf2, Bh[1][2], C1); \
    C0 = MF(Hf3, Bh[0][3], C0);    C1 = MF(Hf3, Bh[1][3], C1); \
    if (l15 < 8) {  /* prefetch x for step J+1 (consumed after next barrier pair) */ \
        int tn = my_off + min(i_ + 1, my_len - 1); \
        const short* xp_ = xs + (size_t)tn * DIM + ql * 8; \
        Pf[0] = *(const bf16x8*)(xp_);      Pf[1] = *(const bf16x8*)(xp_ + 32); \
        Pf[2] = *(const bf16x8*)(xp_ + 64); Pf[3] = *(const bf16x8*)(xp_ + 96); \
    } \
    if (ql < 2) {   /* valid C rows 0..7: scatter gates to gbuf[gate][seq][unit] */ \
        float* gw0 = gbuf + hi8 * 1032 + (ql * 4) * 129 + unit_w; \
        float* gw1 = gbuf + (2 + hi8) * 1032 + (ql * 4) * 129 + unit_w; \
        gw0[0] = C0[0]; gw0[129] = C0[1]; gw0[258] = C0[2]; gw0[387] = C0[3]; \
        gw1[0] = C1[0]; gw1[129] = C1[1]; gw1[258] = C1[2]; gw1[387] = C1[3]; \
    } \
    __syncthreads(); \
    if (i_ < len_g) {   /* wave-uniform: one gate-set per lane */ \
        float gi = gbuf[seq_g * 129 + unit_g]; \
        float gf = gbuf[1032 + seq_g * 129 + unit_g]; \
        float gg = gbuf[2064 + seq_g * 129 + unit_g]; \
        float go = gbuf[3096 + seq_g * 129 + unit_g]; \
        float si = 1.f / (1.f + __expf(-gi)); \
        float sf = 1.f / (1.f + __expf(-gf)); \
        float so = 1.f / (1.f + __expf(-go)); \
        float tg = 1.f - 2.f / (__expf(2.f * gg) + 1.f); \
        float cn = sf * cS + si * tg; \
        float th = 1.f - 2.f / (__expf(2.f * cn) + 1.f); \
        cS = cn; \
        hb[(J) * 1088 + seq_g * 136 + unit_g] = f2b(so * th); \
    } \
    __syncthreads(); \
}

// Persistent per-sequence LSTM: 8 seqs/block, 16 waves (1024 thr), 4 waves/SIMD.
// v7: each wave owns 32 gate-rows (2 N-tiles, 64 weight VGPRs); gate exchange
//     via padded LDS gbuf (no shfl); 1 gate-set/lane with wave-uniform length.
__global__ __launch_bounds__(1024, 4) void lstm_kernel(
        const short* __restrict__ xs, const short* __restrict__ wc,
        short* __restrict__ hstore, const int* __restrict__ seq_off,
        const int* __restrict__ grouped, const int* __restrict__ lengths) {
    __shared__ int s_off[8], s_len[8];
    __shared__ short hchunk[10304];        // 8 slots x 8 seqs x 136 + junk-row pad
    __shared__ float gbuf[4 * 1032];       // [gate][seq][128+pad(129)]
    int tid = threadIdx.x;
    if (tid < 8) {
        int s = grouped[blockIdx.x * 8 + tid];
        s_off[tid] = seq_off[s];
        s_len[tid] = lengths[s];
    }
    for (int j = tid; j < 10304; j += 1024) hchunk[j] = 0;
    __syncthreads();
    int w = tid >> 6, lane = tid & 63, l15 = lane & 15, ql = lane >> 4;
    int hi8 = l15 >> 3;
    int unit_w = w * 8 + (l15 & 7);
    short* hb = hchunk;
    // weight B-frags: wave w owns gates {hi8, 2+hi8} x units [w*8, w*8+8)
    bf16x8 Bx[2][4], Bh[2][4];
    #pragma unroll
    for (int gt = 0; gt < 2; gt++) {
        int j = (2 * gt + hi8) * 128 + unit_w;
        #pragma unroll
        for (int kt = 0; kt < 4; kt++) {
            Bx[gt][kt] = *(const bf16x8*)(wc + j * 256 + kt * 32 + ql * 8);
            Bh[gt][kt] = *(const bf16x8*)(wc + j * 256 + 128 + kt * 32 + ql * 8);
        }
    }
    int maxlen = 0;
    #pragma unroll
    for (int i = 0; i < 8; i++) maxlen = max(maxlen, s_len[i]);
    int my_off = (l15 < 8) ? s_off[l15] : 0;
    int my_len = (l15 < 8) ? s_len[l15] : 1;
    int seq_g = tid >> 7, unit_g = tid & 127;   // gate-set assignment (seq wave-uniform)
    int len_g = s_len[seq_g];
    int off_g = s_off[seq_g];
    float cS = 0.f;
    bf16x8 Pf[4];
    #pragma unroll
    for (int k = 0; k < 4; k++) Pf[k] = (bf16x8){0,0,0,0,0,0,0,0};
    if (l15 < 8) {
        const short* xp = xs + (size_t)my_off * DIM + ql * 8;
        Pf[0] = *(const bf16x8*)(xp);      Pf[1] = *(const bf16x8*)(xp + 32);
        Pf[2] = *(const bf16x8*)(xp + 64); Pf[3] = *(const bf16x8*)(xp + 96);
    }

    int nb8 = (maxlen + 7) >> 3;
    for (int ob = 0; ob < nb8; ob++) {
        int ib8 = ob * 8;
        LSTM_STEP(0)
        LSTM_STEP(1)
        LSTM_STEP(2)
        LSTM_STEP(3)
        LSTM_STEP(4)
        LSTM_STEP(5)
        LSTM_STEP(6)
        LSTM_STEP(7)
        // flush slots 0..7 -> hstore, one b128 per thread; ordered vs next window's
        // slot-0 h-write by step 8's gbuf barrier.
        {
            int st = tid >> 7, s = (tid >> 4) & 7, part = tid & 15;
            int ig = ib8 + st;
            if (ig < s_len[s]) {
                i32x4 v = *(const i32x4*)&hchunk[st * 1088 + s * 136 + part * 8];
                *(i32x4*)(hstore + (size_t)(s_off[s] + ig) * DIM + part * 8) = v;
            }
        }
    }
}

__global__ void ln_kernel(const float* __restrict__ acc, const float* __restrict__ events,
                          const float* __restrict__ g, const float* __restrict__ bta,
                          float* __restrict__ out) {
    int tid = threadIdx.x;
    int wave = tid >> 6, lane = tid & 63;
    int e = blockIdx.x * 4 + wave;
    const float2* a2 = (const float2*)(acc + (size_t)e * DIM);
    const float2* e2 = (const float2*)(events + (size_t)e * DIM);
    float2 av = a2[lane], ev = e2[lane];
    float x0 = av.x + ev.x, x1 = av.y + ev.y;
    float sm = x0 + x1, sq = x0 * x0 + x1 * x1;
    #pragma unroll
    for (int m = 1; m < 64; m <<= 1) {
        sm += __shfl_xor(sm, m, 64);
        sq += __shfl_xor(sq, m, 64);
    }
    float mean = sm * (1.f / DIM);
    float var = sq * (1.f / DIM) - mean * mean;
    float rs = rsqrtf(var + 1e-5f);
    float2 gv = ((const float2*)g)[lane], bv = ((const float2*)bta)[lane];
    float2 ov;
    ov.x = (x0 - mean) * rs * gv.x + bv.x;
    ov.y = (x1 - mean) * rs * gv.y + bv.y;
    ((float2*)(out + (size_t)e * DIM))[lane] = ov;
}

extern "C" void kernel_launch(void* const* d_in, const int* in_sizes, int n_in,
                              void* d_out, int out_size, void* d_ws, size_t ws_size,
                              hipStream_t stream) {
    const float* events = (const float*)d_in[0];
    const float* scat   = (const float*)d_in[1];
    const float* gath   = (const float*)d_in[2];
    const float* wih    = (const float*)d_in[3];
    const float* whh    = (const float*)d_in[4];
    const float* lng    = (const float*)d_in[5];
    const float* lnb    = (const float*)d_in[6];
    const int* posid    = (const int*)d_in[7];
    const int* orig     = (const int*)d_in[8];
    const int* lens     = (const int*)d_in[9];
    char* ws = (char*)d_ws;
    short* evb   = (short*)(ws + OFF_EV);
    short* wcb   = (short*)(ws + OFF_WC);
    short* swb   = (short*)(ws + OFF_SCAT);
    short* gwb   = (short*)(ws + OFF_GATH);
    short* xs    = (short*)(ws + OFF_XS);
    short* hs    = (short*)(ws + OFF_HS);
    int*   klist = (int*)(ws + OFF_KLIST);
    float* acc   = (float*)(ws + OFF_ACC);
    int*   seqo  = (int*)(ws + OFF_SEQOFF);
    int*   grp   = (int*)(ws + OFF_GROUP);
    int*   misc  = (int*)(ws + OFF_MISC);
    int*   bh    = (int*)(ws + OFF_BH);
    float* out   = (float*)d_out;

    convert_kernel<<<8192, 256, 0, stream>>>(events, wih, whh, scat, gath, evb, wcb, swb, gwb, acc);
    hist_kernel<<<NHBLK, 256, 0, stream>>>(posid, bh);
    scan_kernel<<<1, 256, 0, stream>>>(bh, misc);
    setup_kernel<<<1, 256, 0, stream>>>(lens, seqo, grp);
    fill2_kernel<<<NHBLK, 256, 0, stream>>>(posid, bh, misc, klist);
    bucket_gemm<<<NCHUNK_MAX, 256, 0, stream>>>(evb, swb, klist, misc, orig, xs, nullptr, 0);
    lstm_kernel<<<256, 1024, 0, stream>>>(xs, wcb, hs, seqo, grp, lens);
    bucket_gemm<<<NCHUNK_MAX, 256, 0, stream>>>(hs, gwb, klist, misc, orig, nullptr, acc, 1);
    ln_kernel<<<4096, 256, 0, stream>>>(acc, events, lng, lnb, out);
}

// Round 8
// 317.678 us; speedup vs baseline: 1.2032x; 1.2032x over previous
//
#include <hip/hip_runtime.h>

#define N_EVENTS 16384
#define DIM 128
#define NK 9
#define NSEQ 2048
#define TT 147456
#define CHUNK 64
#define NCHUNK_MAX (TT/CHUNK + NK)   // 2313
#define NHBLK 576                    // TT / 256 exactly

typedef __attribute__((ext_vector_type(8))) short bf16x8;
typedef __attribute__((ext_vector_type(4))) float f32x4;
typedef __attribute__((ext_vector_type(4))) int i32x4;

// ---- workspace layout (bytes) ----
#define OFF_EV     0UL                                     // events bf16: 16384*128*2
#define OFF_WC     (OFF_EV   + (size_t)N_EVENTS*DIM*2)     // [w_ih|w_hh] bf16: 512*256*2
#define OFF_SCAT   (OFF_WC   + (size_t)512*256*2)          // scatter_w bf16
#define OFF_GATH   (OFF_SCAT + (size_t)NK*DIM*DIM*2)       // gather_w bf16
#define OFF_XS     (OFF_GATH + (size_t)NK*DIM*DIM*2)       // xs bf16: T*128*2
#define OFF_HS     (OFF_XS   + (size_t)TT*DIM*2)           // h bf16: T*128*2
#define OFF_KLIST  (OFF_HS   + (size_t)TT*DIM*2)           // k-sorted token ids
#define OFF_ACC    (OFF_KLIST+ (size_t)TT*4)               // accum f32: 16384*128*4
#define OFF_SEQOFF (OFF_ACC  + (size_t)N_EVENTS*DIM*4)
#define OFF_GROUP  (OFF_SEQOFF + (size_t)NSEQ*4)
#define OFF_MISC   (OFF_GROUP  + (size_t)NSEQ*4)
#define OFF_BH     (OFF_MISC   + 256UL)                    // blockhist: 576*9 ints
// misc ints: [0..8]=kcount  [32..40]=koff  [48..57]=choff

__device__ __forceinline__ short f2b(float f) {
    union { float f; unsigned u; } v; v.f = f;
    unsigned r = (v.u + 0x7FFFu + ((v.u >> 16) & 1u)) >> 16;
    return (short)r;
}

// sigmoid/tanh via raw v_rcp_f32 — HIP's default IEEE divide is a ~10-instr
// div_scale/div_fmas/div_fixup sequence; 5 divides/gate-set was the hidden
// VALU hog in every round since R2. rel-err ~1e-5 << bf16 rounding.
__device__ __forceinline__ float fsig(float x) {
    return __builtin_amdgcn_rcpf(1.f + __expf(-x));
}
__device__ __forceinline__ float ftanh(float x) {
    return 1.f - 2.f * __builtin_amdgcn_rcpf(__expf(2.f * x) + 1.f);
}

// convert + zero fused: grid covers exactly N_EVENTS*DIM = 2.1M threads
__global__ void convert_kernel(const float* __restrict__ ev, const float* __restrict__ wih,
                               const float* __restrict__ whh, const float* __restrict__ sw,
                               const float* __restrict__ gw,
                               short* __restrict__ evb, short* __restrict__ wcb,
                               short* __restrict__ swb, short* __restrict__ gwb,
                               float* __restrict__ acc) {
    int idx = blockIdx.x * blockDim.x + threadIdx.x;
    if (idx < N_EVENTS * DIM) { evb[idx] = f2b(ev[idx]); acc[idx] = 0.f; }
    if (idx < 512 * DIM) {
        int j = idx >> 7, d = idx & 127;
        wcb[j * 256 + d]       = f2b(wih[idx]);
        wcb[j * 256 + 128 + d] = f2b(whh[idx]);
    }
    if (idx < NK * DIM * DIM) { swb[idx] = f2b(sw[idx]); gwb[idx] = f2b(gw[idx]); }
}

// per-block 9-bin histogram (LDS atomics only — zero global atomics)
__global__ void hist_kernel(const int* __restrict__ pos, int* __restrict__ blockhist) {
    __shared__ int h[NK];
    int tid = threadIdx.x;
    if (tid < NK) h[tid] = 0;
    __syncthreads();
    atomicAdd(&h[pos[blockIdx.x * 256 + tid]], 1);
    __syncthreads();
    if (tid < NK) blockhist[blockIdx.x * NK + tid] = h[tid];
}

// single-block scan: per-block exclusive offsets per bin + global bin/chunk offsets
__global__ void scan_kernel(int* __restrict__ blockhist, int* __restrict__ misc) {
    __shared__ int h[NHBLK * NK];
    int tid = threadIdx.x;
    for (int i = tid; i < NHBLK * NK; i += 256) h[i] = blockhist[i];
    __syncthreads();
    if (tid < NK) {
        int run = 0;
        for (int b = 0; b < NHBLK; b++) {
            int v = h[b * NK + tid];
            h[b * NK + tid] = run;
            run += v;
        }
        misc[tid] = run;                 // total count per k
    }
    __syncthreads();
    if (tid == 0) {
        int ko = 0, co = 0;
        for (int k = 0; k < NK; k++) {
            int c = misc[k];
            misc[32 + k] = ko;
            misc[48 + k] = co;
            ko += c;
            co += (c + CHUNK - 1) / CHUNK;
        }
        misc[48 + NK] = co;
    }
    __syncthreads();
    for (int i = tid; i < NHBLK * NK; i += 256) blockhist[i] = h[i];
}

__global__ void setup_kernel(const int* __restrict__ lengths,
                             int* __restrict__ seq_off, int* __restrict__ grouped) {
    __shared__ int lens[NSEQ];
    __shared__ int tsum[256], tlong[256];
    int tid = threadIdx.x;
    for (int i = tid; i < NSEQ; i += 256) lens[i] = lengths[i];
    __syncthreads();
    int base = tid * 8;
    int ls[8]; int s = 0, lc = 0;
    #pragma unroll
    for (int i = 0; i < 8; i++) { ls[i] = lens[base + i]; s += ls[i]; lc += (ls[i] > 64) ? 1 : 0; }
    tsum[tid] = s; tlong[tid] = lc;
    __syncthreads();
    for (int d = 1; d < 256; d <<= 1) {
        int a = (tid >= d) ? tsum[tid - d] : 0;
        int b = (tid >= d) ? tlong[tid - d] : 0;
        __syncthreads();
        tsum[tid] += a; tlong[tid] += b;
        __syncthreads();
    }
    int nlong_total = tlong[255];
    int excl = tsum[tid] - s;
    int excl_long = tlong[tid] - lc;
    int run = 0, runl = 0;
    #pragma unroll
    for (int i = 0; i < 8; i++) {
        int sid = base + i;
        seq_off[sid] = excl + run;
        int longs_before = excl_long + runl;
        if (ls[i] > 64) { grouped[longs_before] = sid; runl++; }
        else            { grouped[nlong_total + (sid - longs_before)] = sid; }
        run += ls[i];
    }
}

// scatter token ids to their bin positions (LDS atomics for intra-block rank)
__global__ void fill2_kernel(const int* __restrict__ pos, const int* __restrict__ blockhist,
                             const int* __restrict__ misc, int* __restrict__ klist) {
    __shared__ int off[NK];
    int tid = threadIdx.x;
    if (tid < NK) off[tid] = misc[32 + tid] + blockhist[blockIdx.x * NK + tid];
    __syncthreads();
    int t = blockIdx.x * 256 + tid;
    int p = atomicAdd(&off[pos[t]], 1);
    klist[p] = t;
}

// mode 0: rows = events[orig[tok]], write bf16 rows to xs_out[tok]
// mode 1: rows = hstore[tok],       atomicAdd f32 C into acc[orig[tok]]
__global__ void bucket_gemm(const short* __restrict__ src, const short* __restrict__ wall,
                            const int* __restrict__ klist, const int* __restrict__ misc,
                            const int* __restrict__ orig, short* __restrict__ xs_out,
                            float* __restrict__ acc, int mode) {
    const int* chunkoff = misc + 48;
    int b = blockIdx.x;
    if (b >= chunkoff[NK]) return;
    int k = 0;
    while (k < NK - 1 && chunkoff[k + 1] <= b) k++;
    int lc = b - chunkoff[k];
    int cnt = misc[k];
    int base = misc[32 + k] + lc * CHUNK;
    int nv = min(CHUNK, cnt - lc * CHUNK);

    __shared__ int tok[CHUNK], dst[CHUNK];
    __shared__ short A[CHUNK * 136];
    int tid = threadIdx.x;
    if (tid < CHUNK) {
        int tv = klist[base + ((tid < nv) ? tid : 0)];
        tok[tid] = tv;
        dst[tid] = orig[tv];
    }
    __syncthreads();
    {
        int row = tid >> 2, part = tid & 3;
        int ridx = (mode == 0) ? dst[row] : tok[row];
        const i32x4* s4 = (const i32x4*)(src + (size_t)ridx * DIM + part * 32);
        i32x4* d4 = (i32x4*)(A + row * 136 + part * 32);
        d4[0] = s4[0]; d4[1] = s4[1]; d4[2] = s4[2]; d4[3] = s4[3];
    }
    __syncthreads();
    int wave = tid >> 6, lane = tid & 63, l15 = lane & 15, q = lane >> 4;
    const short* wk = wall + (size_t)k * DIM * DIM;
    bf16x8 Bf[2][4];
    #pragma unroll
    for (int nt = 0; nt < 2; nt++) {
        int h = wave * 32 + nt * 16 + l15;
        #pragma unroll
        for (int kt = 0; kt < 4; kt++)
            Bf[nt][kt] = *(const bf16x8*)(wk + h * DIM + kt * 32 + q * 8);
    }
    f32x4 C[4][2];
    #pragma unroll
    for (int mt = 0; mt < 4; mt++)
        #pragma unroll
        for (int nt = 0; nt < 2; nt++) C[mt][nt] = (f32x4){0.f, 0.f, 0.f, 0.f};
    #pragma unroll
    for (int mt = 0; mt < 4; mt++) {
        bf16x8 Afr[4];
        const short* ar = A + (mt * 16 + l15) * 136 + q * 8;
        Afr[0] = *(const bf16x8*)(ar);
        Afr[1] = *(const bf16x8*)(ar + 32);
        Afr[2] = *(const bf16x8*)(ar + 64);
        Afr[3] = *(const bf16x8*)(ar + 96);
        #pragma unroll
        for (int nt = 0; nt < 2; nt++)
            #pragma unroll
            for (int kt = 0; kt < 4; kt++)
                C[mt][nt] = __builtin_amdgcn_mfma_f32_16x16x32_bf16(Afr[kt], Bf[nt][kt], C[mt][nt], 0, 0, 0);
    }
    if (mode == 0) {
        __syncthreads();
        #pragma unroll
        for (int mt = 0; mt < 4; mt++)
            #pragma unroll
            for (int nt = 0; nt < 2; nt++)
                #pragma unroll
                for (int r = 0; r < 4; r++) {
                    int row = mt * 16 + q * 4 + r;
                    int col = wave * 32 + nt * 16 + l15;
                    A[row * 136 + col] = f2b(C[mt][nt][r]);
                }
        __syncthreads();
        int row = tid >> 2, part = tid & 3;
        if (row < nv) {
            const i32x4* s4 = (const i32x4*)(A + row * 136 + part * 32);
            i32x4* d4 = (i32x4*)(xs_out + (size_t)tok[row] * DIM + part * 32);
            d4[0] = s4[0]; d4[1] = s4[1]; d4[2] = s4[2]; d4[3] = s4[3];
        }
    } else {
        #pragma unroll
        for (int mt = 0; mt < 4; mt++)
            #pragma unroll
            for (int nt = 0; nt < 2; nt++)
                #pragma unroll
                for (int r = 0; r < 4; r++) {
                    int row = mt * 16 + q * 4 + r;
                    if (row < nv) {
                        int col = wave * 32 + nt * 16 + l15;
                        atomicAdd(acc + (size_t)dst[row] * DIM + col, C[mt][nt][r]);
                    }
                }
    }
}

#define MF(a, b, c) __builtin_amdgcn_mfma_f32_16x16x32_bf16(a, b, c, 0, 0, 0)

// One LSTM step, fully compile-time slot J (0..7). Ring: step i writes slot i&7,
// reads h from slot (i+7)&7. All LDS addresses = base VGPR + immediate.
#define LSTM_STEP(J, PF) { \
    const int i_ = ib8 + (J); \
    f32x4 Cxi = {0.f,0.f,0.f,0.f}, Cxf = {0.f,0.f,0.f,0.f}; \
    f32x4 Cxg = {0.f,0.f,0.f,0.f}, Cxo = {0.f,0.f,0.f,0.f}; \
    Cxi = MF(PF[0], Bf[0][0], Cxi); Cxf = MF(PF[0], Bf[1][0], Cxf); \
    Cxg = MF(PF[0], Bf[2][0], Cxg); Cxo = MF(PF[0], Bf[3][0], Cxo); \
    Cxi = MF(PF[1], Bf[0][1], Cxi); Cxf = MF(PF[1], Bf[1][1], Cxf); \
    Cxg = MF(PF[1], Bf[2][1], Cxg); Cxo = MF(PF[1], Bf[3][1], Cxo); \
    Cxi = MF(PF[2], Bf[0][2], Cxi); Cxf = MF(PF[2], Bf[1][2], Cxf); \
    Cxg = MF(PF[2], Bf[2][2], Cxg); Cxo = MF(PF[2], Bf[3][2], Cxo); \
    Cxi = MF(PF[3], Bf[0][3], Cxi); Cxf = MF(PF[3], Bf[1][3], Cxf); \
    Cxg = MF(PF[3], Bf[2][3], Cxg); Cxo = MF(PF[3], Bf[3][3], Cxo); \
    bf16x8 Hf0, Hf1, Hf2, Hf3; \
    { const short* hp_ = hb + (((J) + 7) & 7) * 1088 + l15 * 136 + ql * 8; \
      Hf0 = *(const bf16x8*)(hp_);      Hf1 = *(const bf16x8*)(hp_ + 32); \
      Hf2 = *(const bf16x8*)(hp_ + 64); Hf3 = *(const bf16x8*)(hp_ + 96); } \
    f32x4 Chi = {0.f,0.f,0.f,0.f}, Chf = {0.f,0.f,0.f,0.f}; \
    f32x4 Chg = {0.f,0.f,0.f,0.f}, Cho = {0.f,0.f,0.f,0.f}; \
    Chi = MF(Hf0, Bf[0][4], Chi); Chf = MF(Hf0, Bf[1][4], Chf); \
    Chg = MF(Hf0, Bf[2][4], Chg); Cho = MF(Hf0, Bf[3][4], Cho); \
    Chi = MF(Hf1, Bf[0][5], Chi); Chf = MF(Hf1, Bf[1][5], Chf); \
    Chg = MF(Hf1, Bf[2][5], Chg); Cho = MF(Hf1, Bf[3][5], Cho); \
    Chi = MF(Hf2, Bf[0][6], Chi); Chf = MF(Hf2, Bf[1][6], Chf); \
    Chg = MF(Hf2, Bf[2][6], Chg); Cho = MF(Hf2, Bf[3][6], Cho); \
    Chi = MF(Hf3, Bf[0][7], Chi); Chf = MF(Hf3, Bf[1][7], Chf); \
    Chg = MF(Hf3, Bf[2][7], Chg); Cho = MF(Hf3, Bf[3][7], Cho); \
    if (l15 < 8) { \
        const short* xp_ = xs + xoff; \
        PF[0] = *(const bf16x8*)(xp_);      PF[1] = *(const bf16x8*)(xp_ + 32); \
        PF[2] = *(const bf16x8*)(xp_ + 64); PF[3] = *(const bf16x8*)(xp_ + 96); \
    } \
    xoff += ((i_ + 4) <= my_len) ? DIM : 0; \
    f32x4 Gi = Cxi + Chi, Gf = Cxf + Chf, Gg = Cxg + Chg, Go = Cxo + Cho; \
    { \
        int src_ = lane & 31; \
        float i2 = __shfl(Gi[2], src_, 64), i3 = __shfl(Gi[3], src_, 64); \
        float f2 = __shfl(Gf[2], src_, 64), f3 = __shfl(Gf[3], src_, 64); \
        float g2 = __shfl(Gg[2], src_, 64), g3 = __shfl(Gg[3], src_, 64); \
        float o2 = __shfl(Go[2], src_, 64), o3 = __shfl(Go[3], src_, 64); \
        float iA = lo ? Gi[0] : i2, iB = lo ? Gi[1] : i3; \
        float fA = lo ? Gf[0] : f2, fB = lo ? Gf[1] : f3; \
        float gA = lo ? Gg[0] : g2, gB = lo ? Gg[1] : g3; \
        float oA = lo ? Go[0] : o2, oB = lo ? Go[1] : o3; \
        if (i_ < lenA) { \
            float si = fsig(iA), sf = fsig(fA), so = fsig(oA); \
            float tg = ftanh(gA); \
            float cn = sf * cA + si * tg; \
            float th = ftanh(cn); \
            cA = cn; \
            hb[(J) * 1088 + rowA * 136 + u] = f2b(so * th); \
        } \
        if (i_ < lenB) { \
            float si = fsig(iB), sf = fsig(fB), so = fsig(oB); \
            float tg = ftanh(gB); \
            float cn = sf * cB + si * tg; \
            float th = ftanh(cn); \
            cB = cn; \
            hb[(J) * 1088 + rowB * 136 + u] = f2b(so * th); \
        } \
    } \
    __syncthreads(); \
}

// Persistent per-sequence LSTM: 8 seqs/block, 8 waves, weights in VGPR B-frags.
// v8 = v4 (best measured variant) + divisions replaced by v_rcp_f32 intrinsics.
__global__ __launch_bounds__(512, 2) void lstm_kernel(
        const short* __restrict__ xs, const short* __restrict__ wc,
        short* __restrict__ hstore, const int* __restrict__ seq_off,
        const int* __restrict__ grouped, const int* __restrict__ lengths) {
    __shared__ int s_off[8], s_len[8];
    __shared__ short hchunk[11][8][136];   // 8-slot ring + 3 pad slots (junk-row overrun)
    int tid = threadIdx.x;
    if (tid < 8) {
        int s = grouped[blockIdx.x * 8 + tid];
        s_off[tid] = seq_off[s];
        s_len[tid] = lengths[s];
    }
    for (int j = tid; j < 11 * 8 * 136; j += 512) ((short*)hchunk)[j] = 0;
    __syncthreads();
    int lane = tid & 63, l15 = lane & 15, ql = lane >> 4;
    int wave = tid >> 6;
    int u = wave * 16 + l15;                   // hidden unit this lane covers
    short* hb = (short*)hchunk;
    bf16x8 Bf[4][8];                           // [gate][ktile], 128 regs
    #pragma unroll
    for (int g = 0; g < 4; g++) {
        int j = g * 128 + u;
        #pragma unroll
        for (int kt = 0; kt < 8; kt++)
            Bf[g][kt] = *(const bf16x8*)(wc + j * 256 + kt * 32 + ql * 8);
    }
    int maxlen = 0;
    #pragma unroll
    for (int i = 0; i < 8; i++) maxlen = max(maxlen, s_len[i]);
    int my_off = (l15 < 8) ? s_off[l15] : 0;
    int my_len = (l15 < 8) ? s_len[l15] : 1;
    bool lo = (ql < 2);
    int rowA = lo ? (ql * 4 + 0) : ((ql - 2) * 4 + 2);
    int rowB = lo ? (ql * 4 + 1) : ((ql - 2) * 4 + 3);
    int lenA = s_len[rowA], lenB = s_len[rowB];
    float cA = 0.f, cB = 0.f;
    // prefetch distance 2: Pf0 even steps, Pf1 odd steps
    bf16x8 Pf0[4], Pf1[4];
    #pragma unroll
    for (int k = 0; k < 4; k++) { Pf0[k] = (bf16x8){0,0,0,0,0,0,0,0}; Pf1[k] = Pf0[k]; }
    int xoff = my_off * DIM + ql * 8;          // element index, t=0
    if (l15 < 8) {
        const short* xp = xs + xoff;
        Pf0[0] = *(const bf16x8*)(xp);      Pf0[1] = *(const bf16x8*)(xp + 32);
        Pf0[2] = *(const bf16x8*)(xp + 64); Pf0[3] = *(const bf16x8*)(xp + 96);
    }
    int xoff1 = xoff + ((my_len > 1) ? DIM : 0);   // t = min(1, len-1)
    if (l15 < 8) {
        const short* xp = xs + xoff1;
        Pf1[0] = *(const bf16x8*)(xp);      Pf1[1] = *(const bf16x8*)(xp + 32);
        Pf1[2] = *(const bf16x8*)(xp + 64); Pf1[3] = *(const bf16x8*)(xp + 96);
    }
    xoff = xoff1 + ((my_len > 2) ? DIM : 0);       // t = min(2, len-1), next prefetch target

    int nb8 = (maxlen + 7) >> 3;
    for (int ob = 0; ob < nb8; ob++) {
        int ib8 = ob * 8;
        LSTM_STEP(0, Pf0)
        LSTM_STEP(1, Pf1)
        LSTM_STEP(2, Pf0)
        LSTM_STEP(3, Pf1)
        LSTM_STEP(4, Pf0)
        LSTM_STEP(5, Pf1)
        LSTM_STEP(6, Pf0)
        LSTM_STEP(7, Pf1)
        // flush slots 0..7 (steps ib8..ib8+7) -> hstore, coalesced dwordx4
        #pragma unroll
        for (int it = 0; it < 2; it++) {
            int idx = tid + it * 512;
            int st = idx >> 7, s = (idx >> 4) & 7, part = idx & 15;
            int ig = ib8 + st;
            if (ig < s_len[s]) {
                i32x4 v = *(const i32x4*)&hchunk[st][s][part * 8];
                *(i32x4*)(hstore + (size_t)(s_off[s] + ig) * DIM + part * 8) = v;
            }
        }
        __syncthreads();  // flush reads done before next block overwrites slots
    }
}

__global__ void ln_kernel(const float* __restrict__ acc, const float* __restrict__ events,
                          const float* __restrict__ g, const float* __restrict__ bta,
                          float* __restrict__ out) {
    int tid = threadIdx.x;
    int wave = tid >> 6, lane = tid & 63;
    int e = blockIdx.x * 4 + wave;
    const float2* a2 = (const float2*)(acc + (size_t)e * DIM);
    const float2* e2 = (const float2*)(events + (size_t)e * DIM);
    float2 av = a2[lane], ev = e2[lane];
    float x0 = av.x + ev.x, x1 = av.y + ev.y;
    float sm = x0 + x1, sq = x0 * x0 + x1 * x1;
    #pragma unroll
    for (int m = 1; m < 64; m <<= 1) {
        sm += __shfl_xor(sm, m, 64);
        sq += __shfl_xor(sq, m, 64);
    }
    float mean = sm * (1.f / DIM);
    float var = sq * (1.f / DIM) - mean * mean;
    float rs = rsqrtf(var + 1e-5f);
    float2 gv = ((const float2*)g)[lane], bv = ((const float2*)bta)[lane];
    float2 ov;
    ov.x = (x0 - mean) * rs * gv.x + bv.x;
    ov.y = (x1 - mean) * rs * gv.y + bv.y;
    ((float2*)(out + (size_t)e * DIM))[lane] = ov;
}

extern "C" void kernel_launch(void* const* d_in, const int* in_sizes, int n_in,
                              void* d_out, int out_size, void* d_ws, size_t ws_size,
                              hipStream_t stream) {
    const float* events = (const float*)d_in[0];
    const float* scat   = (const float*)d_in[1];
    const float* gath   = (const float*)d_in[2];
    const float* wih    = (const float*)d_in[3];
    const float* whh    = (const float*)d_in[4];
    const float* lng    = (const float*)d_in[5];
    const float* lnb    = (const float*)d_in[6];
    const int* posid    = (const int*)d_in[7];
    const int* orig     = (const int*)d_in[8];
    const int* lens     = (const int*)d_in[9];
    char* ws = (char*)d_ws;
    short* evb   = (short*)(ws + OFF_EV);
    short* wcb   = (short*)(ws + OFF_WC);
    short* swb   = (short*)(ws + OFF_SCAT);
    short* gwb   = (short*)(ws + OFF_GATH);
    short* xs    = (short*)(ws + OFF_XS);
    short* hs    = (short*)(ws + OFF_HS);
    int*   klist = (int*)(ws + OFF_KLIST);
    float* acc   = (float*)(ws + OFF_ACC);
    int*   seqo  = (int*)(ws + OFF_SEQOFF);
    int*   grp   = (int*)(ws + OFF_GROUP);
    int*   misc  = (int*)(ws + OFF_MISC);
    int*   bh    = (int*)(ws + OFF_BH);
    float* out   = (float*)d_out;

    convert_kernel<<<8192, 256, 0, stream>>>(events, wih, whh, scat, gath, evb, wcb, swb, gwb, acc);
    hist_kernel<<<NHBLK, 256, 0, stream>>>(posid, bh);
    scan_kernel<<<1, 256, 0, stream>>>(bh, misc);
    setup_kernel<<<1, 256, 0, stream>>>(lens, seqo, grp);
    fill2_kernel<<<NHBLK, 256, 0, stream>>>(posid, bh, misc, klist);
    bucket_gemm<<<NCHUNK_MAX, 256, 0, stream>>>(evb, swb, klist, misc, orig, xs, nullptr, 0);
    lstm_kernel<<<256, 512, 0, stream>>>(xs, wcb, hs, seqo, grp, lens);
    bucket_gemm<<<NCHUNK_MAX, 256, 0, stream>>>(hs, gwb, klist, misc, orig, nullptr, acc, 1);
    ln_kernel<<<4096, 256, 0, stream>>>(acc, events, lng, lnb, out);
}